// Round 15
// baseline (857.834 us; speedup 1.0000x reference)
//
#include <hip/hip_runtime.h>
#include <hip/hip_bf16.h>
#include <math.h>

#define TPB 256

typedef __attribute__((ext_vector_type(8))) __bf16 bf16x8;
typedef __attribute__((ext_vector_type(4))) __bf16 bf16x4;
typedef __attribute__((ext_vector_type(4))) float f32x4;

// ---- swizzled LDS helpers: byte = row*rowBytes + (byteOff ^ ((row&7)<<4)) ----
static __device__ __forceinline__ bf16x8 lds_frag(const char* base, int row, int byteOff, int rowBytes) {
    return *reinterpret_cast<const bf16x8*>(base + row * rowBytes + (byteOff ^ ((row & 7) << 4)));
}
// packed 4x bf16 write (col0 must be multiple of 4)
static __device__ __forceinline__ void lds_wr4(char* base, int row, int col0, int rowBytes, f32x4 v) {
    bf16x4 p;
    p[0] = (__bf16)v[0]; p[1] = (__bf16)v[1]; p[2] = (__bf16)v[2]; p[3] = (__bf16)v[3];
    *reinterpret_cast<bf16x4*>(base + row * rowBytes + ((col0 << 1) ^ ((row & 7) << 4))) = p;
}

// ws layout: bf16 weights then f32 region
//   wqT@0 (scaled 0.25), wkT@16384, wvT@32768, wpT@49152, w1T@65536 [512][128], w2T@131072 [128][512]
//   f32 @ element 196608: bias_pre[8192] (SWAPPED-scores C-frag layout), bq_s[128]
__global__ void convert_w(const float* __restrict__ wq, const float* __restrict__ wk,
                          const float* __restrict__ wv, const float* __restrict__ wp,
                          const float* __restrict__ w1, const float* __restrict__ w2,
                          const float* __restrict__ rpb, const float* __restrict__ bq,
                          __bf16* __restrict__ ws)
{
    int g = blockIdx.x * 256 + threadIdx.x;
    if (g < 65536) {
        int which = g >> 14, idx = g & 16383, n = idx >> 7, k = idx & 127;
        const float* W = (which == 0) ? wq : (which == 1) ? wk : (which == 2) ? wv : wp;
        float v = W[k * 128 + n];
        if (which == 0) v *= 0.25f;                 // fold score scale into wq
        ws[g] = (__bf16)v;
    } else if (g < 131072) {
        int idx = g - 65536, n = idx >> 7, k = idx & 127;
        ws[g] = (__bf16)w1[k * 512 + n];
    } else if (g < 196608) {
        int idx = g - 131072, n = idx >> 9, k = idx & 511;
        ws[g] = (__bf16)w2[k * 128 + n];
    } else if (g < 204800) {
        // SWAPPED scores: C[m=ktoken][n=packed qrow]; lane=(kg*16+ar), reg r
        float* wsf = (float*)(ws + 196608);
        int g2 = g - 196608;
        int hc = g2 >> 8, h = hc >> 2, ct = hc & 3;
        int lane = (g2 >> 2) & 63, kg = lane >> 4, ar = lane & 15, r = g2 & 3;
        int dy = (ar >> 2) - h + 7;
        int dx = (ar & 3) - (ct * 2 + (kg >> 1)) + 7;
        int hsrc = ((kg & 1) << 2) | r;
        wsf[g2] = rpb[(dy * 15 + dx) * 8 + hsrc];
    } else if (g < 204928) {
        float* wsf = (float*)(ws + 196608);
        wsf[8192 + (g - 204800)] = bq[g - 204800] * 0.25f;
    }
}

// LDS map (bytes) — R14's 50688 layout:
//  A 0..16384     : xn [64]x256B -> (per-wave Q+P @4096+w*2048, attn @12288) -> proj f32[17][132]@0 -> s_h/s_out
//  B 16384..32768 : K [64]x256B -> s_h upper
//  C 32768..49152 : V^T [128]x128B -> xn2 [64]x256B
//  tail: mu, rs, gate, base, vmean(f32)
#define O_P     4096
#define O_ATTN  12288
#define O_K     16384
#define O_VT    32768
#define O_MU    49152
#define O_RS    49408
#define O_GATE  49664
#define O_BASE  49920
#define O_VMEAN 50176
#define SMEM_SZ 50688   // 2KB-granule: 51200 x 3 = 153600 <= 163840

__global__ __launch_bounds__(TPB, 3) void swin_fused_kernel(
    const float* __restrict__ x,
    const __bf16* __restrict__ wqT,               // pre-scaled by 0.25
    const __bf16* __restrict__ wkT, const float* __restrict__ bk,
    const __bf16* __restrict__ wvT, const float* __restrict__ bv,
    const __bf16* __restrict__ wpT, const float* __restrict__ bp,
    const float* __restrict__ bias_pre, const float* __restrict__ bqs,
    const float* __restrict__ ln1g, const float* __restrict__ ln1b,
    const float* __restrict__ ln2g, const float* __restrict__ ln2b,
    const __bf16* __restrict__ w1T, const float* __restrict__ b1,
    const __bf16* __restrict__ w2T, const float* __restrict__ b2,
    const float* __restrict__ gate,
    float* __restrict__ out)
{
    __shared__ __align__(16) char smem[SMEM_SZ];
    char* s_xn   = smem;                 // phase 1-2
    char* s_attn = smem + O_ATTN;
    char* s_k    = smem + O_K;
    char* s_vT   = smem + O_VT;
    char* s_xn2  = smem + O_VT;          // phase 5+
    char* s_h    = smem;                 // phase 6 ([64]x512B)
    float* s_proj = (float*)(smem);      // phase 4-5, f32 [17][132]
    float* s_out  = (float*)(smem);      // phase 8, f32 [64][132]
    float* s_mu   = (float*)(smem + O_MU);
    float* s_rs   = (float*)(smem + O_RS);
    float* s_gate = (float*)(smem + O_GATE);
    int*   s_base = (int*)(smem + O_BASE);
    float* s_vmean = (float*)(smem + O_VMEAN);

    const int tid = threadIdx.x;
    const int blk = blockIdx.x;
    const int b  = blk >> 10;
    const int wh = (blk >> 5) & 31;
    const int ww = blk & 31;

    const int row = tid >> 2;     // token row for per-token phases
    const int l4  = tid & 3;
    const int lane = tid & 63, w = tid >> 6;
    const int ar = lane & 15, kg = lane >> 4;

    // per-wave scratch: Q (cols 0..31) in phase 2/3, then P in phase 3
    char* s_qw = smem + O_P + (w << 11);   // [16]x128B

    float vals[32];               // raw x phases 1-5, x2 phases 5-8

    // ---------- phase 1: load + LN1 (shift folded into addressing) ----------
    {
        const int si = wh * 8 + (row >> 3), sj = ww * 8 + (row & 7);
        const int oi = (si + 4) & 255, oj = (sj + 4) & 255;
        const int base = ((b * 256 + oi) * 256 + oj) * 128;
        if (l4 == 0) { s_base[row] = base; s_gate[row] = gate[oi * 256 + oj]; }
        const float* xp = x + base + l4 * 32;
        float sum = 0.f, sq = 0.f;
#pragma unroll
        for (int i = 0; i < 8; ++i) {
            const float4 v4 = reinterpret_cast<const float4*>(xp)[i];
            vals[4*i+0] = v4.x; vals[4*i+1] = v4.y; vals[4*i+2] = v4.z; vals[4*i+3] = v4.w;
            sum += v4.x + v4.y + v4.z + v4.w;
            sq  += v4.x*v4.x + v4.y*v4.y + v4.z*v4.z + v4.w*v4.w;
        }
        sum += __shfl_xor(sum, 1); sum += __shfl_xor(sum, 2);
        sq  += __shfl_xor(sq , 1); sq  += __shfl_xor(sq , 2);
        const float mu  = sum * (1.f / 128.f);
        const float var = sq * (1.f / 128.f) - mu * mu;
        const float rs  = rsqrtf(var + 1e-5f);
        if (l4 == 0) { s_mu[row] = mu; s_rs[row] = rs; }
#pragma unroll
        for (int j = 0; j < 4; ++j) {
            bf16x8 pk;
#pragma unroll
            for (int e = 0; e < 8; ++e) {
                const int d = l4 * 32 + j * 8 + e;
                pk[e] = (__bf16)((vals[j*8+e] - mu) * rs * ln1g[d] + ln1b[d]);
            }
            const int byteOff = (l4 * 64 + j * 16) ^ ((row & 7) << 4);
            *reinterpret_cast<bf16x8*>(s_xn + row * 256 + byteOff) = pk;
        }
    }
    __syncthreads();

    // ---------- phase 2 (register-lean): Q, then K+V in nt-halves ----------
    {
        // Q swapped -> per-wave scratch (wave w produces heads w, w+4 cols)
        const int nrow = ((ar >> 2) << 3) + (ar & 3);   // unmasked token for packed row ar
        bf16x8 aq[4];
#pragma unroll
        for (int kc = 0; kc < 4; ++kc)
            aq[kc] = lds_frag(s_xn, nrow, kc * 64 + (kg << 4), 256);
#pragma unroll
        for (int ct2 = 0; ct2 < 2; ++ct2) {
            const int m0t = (w + ct2 * 4) * 16;
            bf16x8 af[4];
#pragma unroll
            for (int kc = 0; kc < 4; ++kc)
                af[kc] = *reinterpret_cast<const bf16x8*>(wqT + (m0t + ar) * 128 + kc * 32 + (kg << 3));
            const float4 bb4 = *reinterpret_cast<const float4*>(bqs + m0t + kg * 4);
            f32x4 c = {bb4.x, bb4.y, bb4.z, bb4.w};
#pragma unroll
            for (int kc = 0; kc < 4; ++kc)
                c = __builtin_amdgcn_mfma_f32_16x16x32_bf16(af[kc], aq[kc], c, 0, 0, 0);
            lds_wr4(s_qw, ar, ct2 * 16 + kg * 4, 128, c);
        }

        // K + V over nt-halves with a2[2][4] (halved live frags; fits the 84-reg cap)
        float vs[2] = {0.f, 0.f};
#pragma unroll
        for (int h2 = 0; h2 < 2; ++h2) {
            bf16x8 a2[2][4];
#pragma unroll
            for (int j = 0; j < 2; ++j)
#pragma unroll
                for (int kc = 0; kc < 4; ++kc)
                    a2[j][kc] = lds_frag(s_xn, (h2 * 2 + j) * 16 + ar, kc * 64 + (kg << 4), 256);
#pragma unroll
            for (int ct2 = 0; ct2 < 2; ++ct2) {
                const int m0t = (w + ct2 * 4) * 16;
                // K swapped
                {
                    bf16x8 af[4];
#pragma unroll
                    for (int kc = 0; kc < 4; ++kc)
                        af[kc] = *reinterpret_cast<const bf16x8*>(wkT + (m0t + ar) * 128 + kc * 32 + (kg << 3));
                    const float4 bb4 = *reinterpret_cast<const float4*>(bk + m0t + kg * 4);
#pragma unroll
                    for (int j = 0; j < 2; ++j) {
                        f32x4 c = {bb4.x, bb4.y, bb4.z, bb4.w};
#pragma unroll
                        for (int kc = 0; kc < 4; ++kc)
                            c = __builtin_amdgcn_mfma_f32_16x16x32_bf16(af[kc], a2[j][kc], c, 0, 0, 0);
                        lds_wr4(s_k, (h2 * 2 + j) * 16 + ar, m0t + kg * 4, 256, c);
                    }
                }
                // V unswapped
                {
                    const int brow = m0t + ar;
                    bf16x8 bf[4];
#pragma unroll
                    for (int kc = 0; kc < 4; ++kc)
                        bf[kc] = *reinterpret_cast<const bf16x8*>(wvT + brow * 128 + kc * 32 + (kg << 3));
                    const float bbv = bv[brow];
#pragma unroll
                    for (int j = 0; j < 2; ++j) {
                        f32x4 c = {bbv, bbv, bbv, bbv};
#pragma unroll
                        for (int kc = 0; kc < 4; ++kc)
                            c = __builtin_amdgcn_mfma_f32_16x16x32_bf16(a2[j][kc], bf[kc], c, 0, 0, 0);
                        lds_wr4(s_vT, brow, (h2 * 2 + j) * 16 + kg * 4, 128, c);
                        vs[ct2] += c[0] + c[1] + c[2] + c[3];
                    }
                }
            }
        }
#pragma unroll
        for (int ct2 = 0; ct2 < 2; ++ct2) {
            float v = vs[ct2];
            v += __shfl_xor(v, 16); v += __shfl_xor(v, 32);
            if (kg == 0) s_vmean[(w + ct2 * 4) * 16 + ar] = v * (1.f / 64.f);
        }
    }
    __syncthreads();

    // ---------- phase 3: attention (wave w: heads w, w+4), swapped scores/PV ----------
    char* s_p = s_qw;   // P reuses the per-wave tile (Q read out first)
    bf16x8 aQ01[2];
#pragma unroll
    for (int hi = 0; hi < 2; ++hi) {
        aQ01[hi] = (bf16x8){};
        if (lane < 32) aQ01[hi] = lds_frag(s_qw, ar, hi * 32 + (kg << 4), 128);
    }
#pragma unroll
    for (int hi = 0; hi < 2; ++hi) {
        const int h = w + hi * 4;
        f32x4 sc[4];
#pragma unroll
        for (int ct = 0; ct < 4; ++ct) {
            bf16x8 bK = {};
            if (lane < 32) bK = lds_frag(s_k, ct * 16 + ar, h * 32 + (kg << 4), 256);
            const f32x4 cin = *reinterpret_cast<const f32x4*>(bias_pre + ((h * 4 + ct) << 8) + (lane << 2));
            sc[ct] = __builtin_amdgcn_mfma_f32_16x16x32_bf16(bK, aQ01[hi], cin, 0, 0, 0);
        }
        float sm = 0.f;
#pragma unroll
        for (int ct = 0; ct < 4; ++ct)
#pragma unroll
            for (int r = 0; r < 4; ++r) {
                sc[ct][r] = __expf(sc[ct][r]);
                sm += sc[ct][r];
            }
        sm += __shfl_xor(sm, 16); sm += __shfl_xor(sm, 32);
        const float inv = __builtin_amdgcn_rcpf(sm);
#pragma unroll
        for (int ct = 0; ct < 4; ++ct) {
            f32x4 p4 = {sc[ct][0] * inv, sc[ct][1] * inv, sc[ct][2] * inv, sc[ct][3] * inv};
            lds_wr4(s_p, ar, ct * 16 + kg * 4, 128, p4);
        }
        // PV swapped: C[m=vcol][n=qrow] -> packed write s_attn[qrow][vcol]
        f32x4 o = {0.f, 0.f, 0.f, 0.f};
#pragma unroll
        for (int kc = 0; kc < 2; ++kc) {
            bf16x8 ap = lds_frag(s_p,  ar, kc * 64 + (kg << 4), 128);
            bf16x8 bV = lds_frag(s_vT, h * 16 + ar, kc * 64 + (kg << 4), 128);
            o = __builtin_amdgcn_mfma_f32_16x16x32_bf16(bV, ap, o, 0, 0, 0);
        }
        lds_wr4(s_attn, ar, h * 16 + kg * 4, 256, o);
    }
    __syncthreads();

    // ---------- phase 4: proj (M=16 packed rows) + V_mean proj via VALU dot ----------
    {
        bf16x8 a2[4];
#pragma unroll
        for (int kc = 0; kc < 4; ++kc)
            a2[kc] = lds_frag(s_attn, ar, kc * 64 + (kg << 4), 256);
#pragma unroll
        for (int ct2 = 0; ct2 < 2; ++ct2) {
            const int brow = (w + ct2 * 4) * 16 + ar;
            bf16x8 bf[4];
#pragma unroll
            for (int kc = 0; kc < 4; ++kc)
                bf[kc] = *reinterpret_cast<const bf16x8*>(wpT + brow * 128 + kc * 32 + (kg << 3));
            const float bb = bp[brow];
            f32x4 c = {bb, bb, bb, bb};
#pragma unroll
            for (int kc = 0; kc < 4; ++kc)
                c = __builtin_amdgcn_mfma_f32_16x16x32_bf16(a2[kc], bf[kc], c, 0, 0, 0);
#pragma unroll
            for (int r = 0; r < 4; ++r)
                s_proj[(kg * 4 + r) * 132 + brow] = c[r];
        }
        // V_mean proj row (threads 0..127, one output col each)
        if (tid < 128) {
            const int col = tid;
            float acc = bp[col];
#pragma unroll
            for (int j = 0; j < 16; ++j) {
                const bf16x8 w8 = *reinterpret_cast<const bf16x8*>(wpT + col * 128 + j * 8);
#pragma unroll
                for (int e = 0; e < 8; ++e)
                    acc += s_vmean[j * 8 + e] * (float)w8[e];
            }
            s_proj[16 * 132 + col] = acc;
        }
    }
    __syncthreads();

    // ---------- phase 5: assemble x2 (f32 xn recompute) + LN2 -> xn2 into C ----------
    {
        const float sg = 1.f / (1.f + __expf(-s_gate[row]));
        const float mu1 = s_mu[row], rs1 = s_rs[row];
        const bool masked = ((row >> 3) >= 4) || ((row & 7) >= 4);
        const int prow = masked ? 16 : ((row >> 3) * 4 + (row & 7));
        const float* pr = s_proj + prow * 132 + l4 * 32;
        const float* g1  = ln1g + l4 * 32;
        const float* b1v = ln1b + l4 * 32;
        float sum = 0.f, sq = 0.f;
#pragma unroll
        for (int i = 0; i < 8; ++i) {
            const float4 gg = reinterpret_cast<const float4*>(g1)[i];
            const float4 bb = reinterpret_cast<const float4*>(b1v)[i];
            const float g4[4] = {gg.x, gg.y, gg.z, gg.w};
            const float b4[4] = {bb.x, bb.y, bb.z, bb.w};
#pragma unroll
            for (int c = 0; c < 4; ++c) {
                const int idx = 4*i + c;
                const float xv = vals[idx];
                const float xnv = (xv - mu1) * rs1 * g4[c] + b4[c];
                const float x2 = xnv + pr[idx] + sg * xv;
                vals[idx] = x2;
                sum += x2; sq += x2 * x2;
            }
        }
        sum += __shfl_xor(sum, 1); sum += __shfl_xor(sum, 2);
        sq  += __shfl_xor(sq , 1); sq  += __shfl_xor(sq , 2);
        const float mu  = sum * (1.f / 128.f);
        const float var = sq * (1.f / 128.f) - mu * mu;
        const float rs  = rsqrtf(var + 1e-5f);
        // xn2 writes (region C) are disjoint from s_proj reads (region A): no barrier needed
#pragma unroll
        for (int j = 0; j < 4; ++j) {
            bf16x8 pk;
#pragma unroll
            for (int e = 0; e < 8; ++e) {
                const int d = l4 * 32 + j * 8 + e;
                pk[e] = (__bf16)((vals[j*8+e] - mu) * rs * ln2g[d] + ln2b[d]);
            }
            const int byteOff = (l4 * 64 + j * 16) ^ ((row & 7) << 4);
            *reinterpret_cast<bf16x8*>(s_xn2 + row * 256 + byteOff) = pk;
        }
    }
    __syncthreads();

    // ---------- phase 6/7: MLP, GEMM1 swapped in nt-chunks, hidden in 2 halves ----------
    f32x4 acc2[2][4];
#pragma unroll
    for (int ct2 = 0; ct2 < 2; ++ct2) {
        const float bb = b2[(w + ct2 * 4) * 16 + ar];
#pragma unroll
        for (int rt = 0; rt < 4; ++rt) acc2[ct2][rt] = {bb, bb, bb, bb};
    }

#pragma unroll
    for (int hh = 0; hh < 2; ++hh) {
        // GEMM1 swapped: C[m=hidden][n=token] -> gelu -> packed write h[token][hidden]
#pragma unroll
        for (int ntc = 0; ntc < 2; ++ntc) {
            bf16x8 bx2[2][4];
#pragma unroll
            for (int j = 0; j < 2; ++j)
#pragma unroll
                for (int kc = 0; kc < 4; ++kc)
                    bx2[j][kc] = lds_frag(s_xn2, (ntc * 2 + j) * 16 + ar, kc * 64 + (kg << 4), 256);
#pragma unroll
            for (int i = 0; i < 4; ++i) {
                const int hcol0 = (w + 4 * i) * 16;         // within-half hidden base
                const int m0g = hh * 256 + hcol0;           // global hidden base
                bf16x8 af[4];
#pragma unroll
                for (int kc = 0; kc < 4; ++kc)
                    af[kc] = *reinterpret_cast<const bf16x8*>(w1T + (m0g + ar) * 128 + kc * 32 + (kg << 3));
                const float4 bb4 = *reinterpret_cast<const float4*>(b1 + m0g + kg * 4);
#pragma unroll
                for (int j = 0; j < 2; ++j) {
                    f32x4 c = {bb4.x, bb4.y, bb4.z, bb4.w};
#pragma unroll
                    for (int kc = 0; kc < 4; ++kc)
                        c = __builtin_amdgcn_mfma_f32_16x16x32_bf16(af[kc], bx2[j][kc], c, 0, 0, 0);
                    f32x4 g4;
#pragma unroll
                    for (int r = 0; r < 4; ++r) {
                        const float v = c[r];
                        const float u = v * fmaf(0.044715f, v * v, 1.0f);
                        const float e = __expf(-1.5957691216057308f * u);   // exp(-2t)
                        g4[r] = v * __builtin_amdgcn_rcpf(1.0f + e);        // v*sigmoid(2t)
                    }
                    lds_wr4(s_h, (ntc * 2 + j) * 16 + ar, hcol0 + kg * 4, 512, g4);
                }
            }
        }
        __syncthreads();
        // GEMM2 partial: y += h_half @ w2[hh*256..]
#pragma unroll
        for (int kc = 0; kc < 8; ++kc) {
            bf16x8 ah[4];
#pragma unroll
            for (int rt = 0; rt < 4; ++rt)
                ah[rt] = lds_frag(s_h, rt * 16 + ar, kc * 64 + (kg << 4), 512);
#pragma unroll
            for (int ct2 = 0; ct2 < 2; ++ct2) {
                const int brow = (w + ct2 * 4) * 16 + ar;
                const bf16x8 bw = *reinterpret_cast<const bf16x8*>(w2T + brow * 512 + hh * 256 + kc * 32 + (kg << 3));
#pragma unroll
                for (int rt = 0; rt < 4; ++rt)
                    acc2[ct2][rt] = __builtin_amdgcn_mfma_f32_16x16x32_bf16(ah[rt], bw, acc2[ct2][rt], 0, 0, 0);
            }
        }
        __syncthreads();
    }

    // ---------- phase 8: stage MLP out (f32 [64][132] @ smem+0), final write ----------
#pragma unroll
    for (int ct2 = 0; ct2 < 2; ++ct2)
#pragma unroll
        for (int rt = 0; rt < 4; ++rt)
#pragma unroll
            for (int r = 0; r < 4; ++r)
                s_out[(rt * 16 + kg * 4 + r) * 132 + (w + ct2 * 4) * 16 + ar] = acc2[ct2][rt][r];
    __syncthreads();
    {
        const int base = s_base[row];
        float* op = out + base + l4 * 32;
        const float* po = s_out + row * 132 + l4 * 32;
#pragma unroll
        for (int i = 0; i < 8; ++i) {
            float4 o;
            o.x = vals[4*i+0] + po[4*i+0];
            o.y = vals[4*i+1] + po[4*i+1];
            o.z = vals[4*i+2] + po[4*i+2];
            o.w = vals[4*i+3] + po[4*i+3];
            reinterpret_cast<float4*>(op)[i] = o;
        }
    }
}

extern "C" void kernel_launch(void* const* d_in, const int* in_sizes, int n_in,
                              void* d_out, int out_size, void* d_ws, size_t ws_size,
                              hipStream_t stream) {
    (void)in_sizes; (void)n_in; (void)ws_size; (void)out_size;
    const float* x    = (const float*)d_in[0];
    const float* wq   = (const float*)d_in[1];
    const float* bq   = (const float*)d_in[2];
    const float* wk   = (const float*)d_in[3];
    const float* bk   = (const float*)d_in[4];
    const float* wv   = (const float*)d_in[5];
    const float* bv   = (const float*)d_in[6];
    const float* wp   = (const float*)d_in[7];
    const float* bp   = (const float*)d_in[8];
    const float* rpb  = (const float*)d_in[9];
    const float* ln1g = (const float*)d_in[10];
    const float* ln1b = (const float*)d_in[11];
    const float* ln2g = (const float*)d_in[12];
    const float* ln2b = (const float*)d_in[13];
    const float* w1   = (const float*)d_in[14];
    const float* b1   = (const float*)d_in[15];
    const float* w2   = (const float*)d_in[16];
    const float* b2   = (const float*)d_in[17];
    const float* gate = (const float*)d_in[18];
    float* out = (float*)d_out;

    __bf16* ws = (__bf16*)d_ws;
    const __bf16* wqT = ws;
    const __bf16* wkT = ws + 16384;
    const __bf16* wvT = ws + 32768;
    const __bf16* wpT = ws + 49152;
    const __bf16* w1T = ws + 65536;
    const __bf16* w2T = ws + 131072;
    const float* wsf  = (const float*)(ws + 196608);
    const float* bias_pre = wsf;
    const float* bqs      = wsf + 8192;

    convert_w<<<801, 256, 0, stream>>>(wq, wk, wv, wp, w1, w2, rpb, bq, ws);
    swin_fused_kernel<<<8192, TPB, 0, stream>>>(x, wqT, wkT, bk, wvT, bv, wpT, bp,
                                                bias_pre, bqs, ln1g, ln1b, ln2g, ln2b,
                                                w1T, b1, w2T, b2, gate, out);
}

// Round 16
// 660.728 us; speedup vs baseline: 1.2983x; 1.2983x over previous
//
#include <hip/hip_runtime.h>
#include <hip/hip_bf16.h>
#include <math.h>

#define TPB 256

typedef __attribute__((ext_vector_type(8))) __bf16 bf16x8;
typedef __attribute__((ext_vector_type(4))) __bf16 bf16x4;
typedef __attribute__((ext_vector_type(4))) float f32x4;

// ---- swizzled LDS helpers: byte = row*rowBytes + (byteOff ^ ((row&7)<<4)) ----
static __device__ __forceinline__ bf16x8 lds_frag(const char* base, int row, int byteOff, int rowBytes) {
    return *reinterpret_cast<const bf16x8*>(base + row * rowBytes + (byteOff ^ ((row & 7) << 4)));
}
// packed 4x bf16 write (col0 must be multiple of 4)
static __device__ __forceinline__ void lds_wr4(char* base, int row, int col0, int rowBytes, f32x4 v) {
    bf16x4 p;
    p[0] = (__bf16)v[0]; p[1] = (__bf16)v[1]; p[2] = (__bf16)v[2]; p[3] = (__bf16)v[3];
    *reinterpret_cast<bf16x4*>(base + row * rowBytes + ((col0 << 1) ^ ((row & 7) << 4))) = p;
}

// ws layout: bf16 weights then f32 region
//   wqT@0 (scaled 0.25), wkT@16384, wvT@32768, wpT@49152, w1T@65536 [512][128], w2T@131072 [128][512]
//   f32 @ element 196608: bias_pre[8192] (SWAPPED-scores C-frag layout), bq_s[128]
__global__ void convert_w(const float* __restrict__ wq, const float* __restrict__ wk,
                          const float* __restrict__ wv, const float* __restrict__ wp,
                          const float* __restrict__ w1, const float* __restrict__ w2,
                          const float* __restrict__ rpb, const float* __restrict__ bq,
                          __bf16* __restrict__ ws)
{
    int g = blockIdx.x * 256 + threadIdx.x;
    if (g < 65536) {
        int which = g >> 14, idx = g & 16383, n = idx >> 7, k = idx & 127;
        const float* W = (which == 0) ? wq : (which == 1) ? wk : (which == 2) ? wv : wp;
        float v = W[k * 128 + n];
        if (which == 0) v *= 0.25f;                 // fold score scale into wq
        ws[g] = (__bf16)v;
    } else if (g < 131072) {
        int idx = g - 65536, n = idx >> 7, k = idx & 127;
        ws[g] = (__bf16)w1[k * 512 + n];
    } else if (g < 196608) {
        int idx = g - 131072, n = idx >> 9, k = idx & 511;
        ws[g] = (__bf16)w2[k * 128 + n];
    } else if (g < 204800) {
        // SWAPPED scores: C[m=ktoken][n=packed qrow]; lane=(kg*16+ar), reg r
        float* wsf = (float*)(ws + 196608);
        int g2 = g - 196608;
        int hc = g2 >> 8, h = hc >> 2, ct = hc & 3;
        int lane = (g2 >> 2) & 63, kg = lane >> 4, ar = lane & 15, r = g2 & 3;
        int dy = (ar >> 2) - h + 7;
        int dx = (ar & 3) - (ct * 2 + (kg >> 1)) + 7;
        int hsrc = ((kg & 1) << 2) | r;
        wsf[g2] = rpb[(dy * 15 + dx) * 8 + hsrc];
    } else if (g < 204928) {
        float* wsf = (float*)(ws + 196608);
        wsf[8192 + (g - 204800)] = bq[g - 204800] * 0.25f;
    }
}

// LDS map (bytes) — R13 layout:
//  A 0..16384     : xn [64]x256B -> (P @4096+w*2048, attn @12288) -> proj f32[17][132]@0 -> s_h/s_out
//  B 16384..32768 : K [64]x256B -> s_h upper
//  C 32768..49152 : V^T [128]x128B -> xn2 [64]x256B
//  Q 49152..53248 : [16]x256B (dedicated)
//  tail: mu, rs, gate, base, vmean(f32)
#define O_P     4096
#define O_ATTN  12288
#define O_K     16384
#define O_VT    32768
#define O_Q     49152
#define O_MU    53248
#define O_RS    53504
#define O_GATE  53760
#define O_BASE  54016
#define O_VMEAN 54272
#define SMEM_SZ 54784

__global__ __launch_bounds__(TPB, 2) void swin_fused_kernel(
    const float* __restrict__ x,
    const __bf16* __restrict__ wqT,               // pre-scaled by 0.25
    const __bf16* __restrict__ wkT, const float* __restrict__ bk,
    const __bf16* __restrict__ wvT, const float* __restrict__ bv,
    const __bf16* __restrict__ wpT, const float* __restrict__ bp,
    const float* __restrict__ bias_pre, const float* __restrict__ bqs,
    const float* __restrict__ ln1g, const float* __restrict__ ln1b,
    const float* __restrict__ ln2g, const float* __restrict__ ln2b,
    const __bf16* __restrict__ w1T, const float* __restrict__ b1,
    const __bf16* __restrict__ w2T, const float* __restrict__ b2,
    const float* __restrict__ gate,
    float* __restrict__ out)
{
    __shared__ __align__(16) char smem[SMEM_SZ];
    char* s_xn   = smem;                 // phase 1-2
    char* s_attn = smem + O_ATTN;
    char* s_k    = smem + O_K;
    char* s_vT   = smem + O_VT;
    char* s_xn2  = smem + O_VT;          // phase 5+
    char* s_q    = smem + O_Q;
    char* s_h    = smem;                 // phase 6 ([64]x512B)
    float* s_proj = (float*)(smem);      // phase 4-5, f32 [17][132]
    float* s_out  = (float*)(smem);      // phase 8, f32 [64][132]
    float* s_mu   = (float*)(smem + O_MU);
    float* s_rs   = (float*)(smem + O_RS);
    float* s_gate = (float*)(smem + O_GATE);
    int*   s_base = (int*)(smem + O_BASE);
    float* s_vmean = (float*)(smem + O_VMEAN);

    const int tid = threadIdx.x;
    const int blk = blockIdx.x;
    const int b  = blk >> 10;
    const int wh = (blk >> 5) & 31;
    const int ww = blk & 31;

    const int row = tid >> 2;     // token row for per-token phases
    const int l4  = tid & 3;
    const int lane = tid & 63, w = tid >> 6;
    const int ar = lane & 15, kg = lane >> 4;

    float vals[32];               // raw x phases 1-5, x2 phases 5-8

    // ---------- phase 1: load + LN1 (shift folded into addressing) ----------
    {
        const int si = wh * 8 + (row >> 3), sj = ww * 8 + (row & 7);
        const int oi = (si + 4) & 255, oj = (sj + 4) & 255;
        const int base = ((b * 256 + oi) * 256 + oj) * 128;
        if (l4 == 0) { s_base[row] = base; s_gate[row] = gate[oi * 256 + oj]; }
        const float* xp = x + base + l4 * 32;
        float sum = 0.f, sq = 0.f;
#pragma unroll
        for (int i = 0; i < 8; ++i) {
            const float4 v4 = reinterpret_cast<const float4*>(xp)[i];
            vals[4*i+0] = v4.x; vals[4*i+1] = v4.y; vals[4*i+2] = v4.z; vals[4*i+3] = v4.w;
            sum += v4.x + v4.y + v4.z + v4.w;
            sq  += v4.x*v4.x + v4.y*v4.y + v4.z*v4.z + v4.w*v4.w;
        }
        sum += __shfl_xor(sum, 1); sum += __shfl_xor(sum, 2);
        sq  += __shfl_xor(sq , 1); sq  += __shfl_xor(sq , 2);
        const float mu  = sum * (1.f / 128.f);
        const float var = sq * (1.f / 128.f) - mu * mu;
        const float rs  = rsqrtf(var + 1e-5f);
        if (l4 == 0) { s_mu[row] = mu; s_rs[row] = rs; }
#pragma unroll
        for (int j = 0; j < 4; ++j) {
            bf16x8 pk;
#pragma unroll
            for (int e = 0; e < 8; ++e) {
                const int d = l4 * 32 + j * 8 + e;
                pk[e] = (__bf16)((vals[j*8+e] - mu) * rs * ln1g[d] + ln1b[d]);
            }
            const int byteOff = (l4 * 64 + j * 16) ^ ((row & 7) << 4);
            *reinterpret_cast<bf16x8*>(s_xn + row * 256 + byteOff) = pk;
        }
    }

    // ---- prefetch phase-2 K/V weights + biases (pure global reg-loads) ----
    bf16x8 pfk[2][4], pfv[2][4];
    float4 pfbk[2];
    float  pfbv[2];
#pragma unroll
    for (int ct2 = 0; ct2 < 2; ++ct2) {
        const int m0t = (w + ct2 * 4) * 16;
#pragma unroll
        for (int kc = 0; kc < 4; ++kc) {
            pfk[ct2][kc] = *reinterpret_cast<const bf16x8*>(wkT + (m0t + ar) * 128 + kc * 32 + (kg << 3));
            pfv[ct2][kc] = *reinterpret_cast<const bf16x8*>(wvT + (m0t + ar) * 128 + kc * 32 + (kg << 3));
        }
        pfbk[ct2] = *reinterpret_cast<const float4*>(bk + m0t + kg * 4);
        pfbv[ct2] = bv[m0t + ar];
    }
    __syncthreads();

    // ---------- phase 2 (merged): K + V + Q GEMMs ----------
    f32x4 pfcin[2][4];   // bias_pre prefetch for phase 3
    {
        bf16x8 a[4][4];    // xn token-tiles (B-operand for swapped GEMMs)
#pragma unroll
        for (int nt = 0; nt < 4; ++nt)
#pragma unroll
            for (int kc = 0; kc < 4; ++kc)
                a[nt][kc] = lds_frag(s_xn, nt * 16 + ar, kc * 64 + (kg << 4), 256);
        const int nrow = ((ar >> 2) << 3) + (ar & 3);   // unmasked token for packed row ar
        bf16x8 aq[4];
#pragma unroll
        for (int kc = 0; kc < 4; ++kc)
            aq[kc] = lds_frag(s_xn, nrow, kc * 64 + (kg << 4), 256);

        // K swapped: C[m=kcol][n=token] -> packed writes s_k[token][kcol]
#pragma unroll
        for (int ct2 = 0; ct2 < 2; ++ct2) {
            const int m0t = (w + ct2 * 4) * 16;
#pragma unroll
            for (int nt = 0; nt < 4; ++nt) {
                f32x4 c = {pfbk[ct2].x, pfbk[ct2].y, pfbk[ct2].z, pfbk[ct2].w};
#pragma unroll
                for (int kc = 0; kc < 4; ++kc)
                    c = __builtin_amdgcn_mfma_f32_16x16x32_bf16(pfk[ct2][kc], a[nt][kc], c, 0, 0, 0);
                lds_wr4(s_k, nt * 16 + ar, m0t + kg * 4, 256, c);
            }
        }
        // V unswapped: C[m=token][n=vcol] -> packed writes s_vT[vcol][token] + col-mean
#pragma unroll
        for (int ct2 = 0; ct2 < 2; ++ct2) {
            const int brow = (w + ct2 * 4) * 16 + ar;
            const float bb = pfbv[ct2];
            float vs = 0.f;
#pragma unroll
            for (int rt = 0; rt < 4; ++rt) {
                f32x4 c = {bb, bb, bb, bb};
#pragma unroll
                for (int kc = 0; kc < 4; ++kc)
                    c = __builtin_amdgcn_mfma_f32_16x16x32_bf16(a[rt][kc], pfv[ct2][kc], c, 0, 0, 0);
                lds_wr4(s_vT, brow, rt * 16 + kg * 4, 128, c);
                vs += c[0] + c[1] + c[2] + c[3];
            }
            vs += __shfl_xor(vs, 16); vs += __shfl_xor(vs, 32);
            if (kg == 0) s_vmean[brow] = vs * (1.f / 64.f);
        }
        // Q swapped -> dedicated s_q region
#pragma unroll
        for (int ct2 = 0; ct2 < 2; ++ct2) {
            const int m0t = (w + ct2 * 4) * 16;
            bf16x8 af[4];
#pragma unroll
            for (int kc = 0; kc < 4; ++kc)
                af[kc] = *reinterpret_cast<const bf16x8*>(wqT + (m0t + ar) * 128 + kc * 32 + (kg << 3));
            const float4 bb4 = *reinterpret_cast<const float4*>(bqs + m0t + kg * 4);
            f32x4 c = {bb4.x, bb4.y, bb4.z, bb4.w};
#pragma unroll
            for (int kc = 0; kc < 4; ++kc)
                c = __builtin_amdgcn_mfma_f32_16x16x32_bf16(af[kc], aq[kc], c, 0, 0, 0);
            lds_wr4(s_q, ar, m0t + kg * 4, 256, c);
        }
        // prefetch phase-3 bias_pre fragments
#pragma unroll
        for (int hi = 0; hi < 2; ++hi) {
            const int h = w + hi * 4;
#pragma unroll
            for (int ct = 0; ct < 4; ++ct)
                pfcin[hi][ct] = *reinterpret_cast<const f32x4*>(bias_pre + ((h * 4 + ct) << 8) + (lane << 2));
        }
    }
    __syncthreads();

    // ---------- phase 3: attention (wave w: heads w, w+4), swapped scores/PV ----------
    char* s_p = smem + O_P + (w << 11);
#pragma unroll
    for (int hi = 0; hi < 2; ++hi) {
        const int h = w + hi * 4;
        bf16x8 aQ = {};
        if (lane < 32) aQ = lds_frag(s_q, ar, h * 32 + (kg << 4), 256);
        f32x4 sc[4];
#pragma unroll
        for (int ct = 0; ct < 4; ++ct) {
            bf16x8 bK = {};
            if (lane < 32) bK = lds_frag(s_k, ct * 16 + ar, h * 32 + (kg << 4), 256);
            sc[ct] = __builtin_amdgcn_mfma_f32_16x16x32_bf16(bK, aQ, pfcin[hi][ct], 0, 0, 0);
        }
        float sm = 0.f;
#pragma unroll
        for (int ct = 0; ct < 4; ++ct)
#pragma unroll
            for (int r = 0; r < 4; ++r) {
                sc[ct][r] = __expf(sc[ct][r]);
                sm += sc[ct][r];
            }
        sm += __shfl_xor(sm, 16); sm += __shfl_xor(sm, 32);
        const float inv = __builtin_amdgcn_rcpf(sm);
#pragma unroll
        for (int ct = 0; ct < 4; ++ct) {
            f32x4 p4 = {sc[ct][0] * inv, sc[ct][1] * inv, sc[ct][2] * inv, sc[ct][3] * inv};
            lds_wr4(s_p, ar, ct * 16 + kg * 4, 128, p4);
        }
        // PV swapped: C[m=vcol][n=qrow] -> packed write s_attn[qrow][vcol]
        f32x4 o = {0.f, 0.f, 0.f, 0.f};
#pragma unroll
        for (int kc = 0; kc < 2; ++kc) {
            bf16x8 ap = lds_frag(s_p,  ar, kc * 64 + (kg << 4), 128);
            bf16x8 bV = lds_frag(s_vT, h * 16 + ar, kc * 64 + (kg << 4), 128);
            o = __builtin_amdgcn_mfma_f32_16x16x32_bf16(bV, ap, o, 0, 0, 0);
        }
        lds_wr4(s_attn, ar, h * 16 + kg * 4, 256, o);
    }
    // ---- prefetch phase-4 proj weights ----
    bf16x8 pfp[2][4];
    float  pfbp[2];
#pragma unroll
    for (int ct2 = 0; ct2 < 2; ++ct2) {
        const int brow = (w + ct2 * 4) * 16 + ar;
#pragma unroll
        for (int kc = 0; kc < 4; ++kc)
            pfp[ct2][kc] = *reinterpret_cast<const bf16x8*>(wpT + brow * 128 + kc * 32 + (kg << 3));
        pfbp[ct2] = bp[brow];
    }
    __syncthreads();

    // ---------- phase 4: proj (M=16 packed rows) + V_mean proj via VALU dot ----------
    {
        bf16x8 a2[4];
#pragma unroll
        for (int kc = 0; kc < 4; ++kc)
            a2[kc] = lds_frag(s_attn, ar, kc * 64 + (kg << 4), 256);
#pragma unroll
        for (int ct2 = 0; ct2 < 2; ++ct2) {
            const int brow = (w + ct2 * 4) * 16 + ar;
            const float bb = pfbp[ct2];
            f32x4 c = {bb, bb, bb, bb};
#pragma unroll
            for (int kc = 0; kc < 4; ++kc)
                c = __builtin_amdgcn_mfma_f32_16x16x32_bf16(a2[kc], pfp[ct2][kc], c, 0, 0, 0);
#pragma unroll
            for (int r = 0; r < 4; ++r)
                s_proj[(kg * 4 + r) * 132 + brow] = c[r];
        }
        // V_mean proj row (threads 0..127, one output col each)
        if (tid < 128) {
            const int col = tid;
            float acc = bp[col];
#pragma unroll
            for (int j = 0; j < 16; ++j) {
                const bf16x8 w8 = *reinterpret_cast<const bf16x8*>(wpT + col * 128 + j * 8);
#pragma unroll
                for (int e = 0; e < 8; ++e)
                    acc += s_vmean[j * 8 + e] * (float)w8[e];
            }
            s_proj[16 * 132 + col] = acc;
        }
    }
    __syncthreads();

    // ---- prefetch first GEMM1 weight tile (hh=0, i=0) — hides under phase-5 VALU ----
    bf16x8 pfw1[4];
    float4 pfb1;
    {
        const int m0g0 = w * 16;
#pragma unroll
        for (int kc = 0; kc < 4; ++kc)
            pfw1[kc] = *reinterpret_cast<const bf16x8*>(w1T + (m0g0 + ar) * 128 + kc * 32 + (kg << 3));
        pfb1 = *reinterpret_cast<const float4*>(b1 + m0g0 + kg * 4);
    }

    // ---------- phase 5: assemble x2 (f32 xn recompute) + LN2 -> xn2 into C ----------
    {
        const float sg = 1.f / (1.f + __expf(-s_gate[row]));
        const float mu1 = s_mu[row], rs1 = s_rs[row];
        const bool masked = ((row >> 3) >= 4) || ((row & 7) >= 4);
        const int prow = masked ? 16 : ((row >> 3) * 4 + (row & 7));
        const float* pr = s_proj + prow * 132 + l4 * 32;
        const float* g1  = ln1g + l4 * 32;
        const float* b1v = ln1b + l4 * 32;
        float sum = 0.f, sq = 0.f;
#pragma unroll
        for (int i = 0; i < 8; ++i) {
            const float4 gg = reinterpret_cast<const float4*>(g1)[i];
            const float4 bb = reinterpret_cast<const float4*>(b1v)[i];
            const float g4[4] = {gg.x, gg.y, gg.z, gg.w};
            const float b4[4] = {bb.x, bb.y, bb.z, bb.w};
#pragma unroll
            for (int c = 0; c < 4; ++c) {
                const int idx = 4*i + c;
                const float xv = vals[idx];
                const float xnv = (xv - mu1) * rs1 * g4[c] + b4[c];
                const float x2 = xnv + pr[idx] + sg * xv;
                vals[idx] = x2;
                sum += x2; sq += x2 * x2;
            }
        }
        sum += __shfl_xor(sum, 1); sum += __shfl_xor(sum, 2);
        sq  += __shfl_xor(sq , 1); sq  += __shfl_xor(sq , 2);
        const float mu  = sum * (1.f / 128.f);
        const float var = sq * (1.f / 128.f) - mu * mu;
        const float rs  = rsqrtf(var + 1e-5f);
        // xn2 writes (region C) are disjoint from s_proj reads (region A): no barrier needed
#pragma unroll
        for (int j = 0; j < 4; ++j) {
            bf16x8 pk;
#pragma unroll
            for (int e = 0; e < 8; ++e) {
                const int d = l4 * 32 + j * 8 + e;
                pk[e] = (__bf16)((vals[j*8+e] - mu) * rs * ln2g[d] + ln2b[d]);
            }
            const int byteOff = (l4 * 64 + j * 16) ^ ((row & 7) << 4);
            *reinterpret_cast<bf16x8*>(s_xn2 + row * 256 + byteOff) = pk;
        }
    }
    __syncthreads();

    // ---------- phase 6/7: MLP, GEMM1 swapped (packed h writes), hidden in 2 halves ----------
    bf16x8 bx[4][4];
#pragma unroll
    for (int nt = 0; nt < 4; ++nt)
#pragma unroll
        for (int kc = 0; kc < 4; ++kc)
            bx[nt][kc] = lds_frag(s_xn2, nt * 16 + ar, kc * 64 + (kg << 4), 256);

    f32x4 acc2[2][4];
#pragma unroll
    for (int ct2 = 0; ct2 < 2; ++ct2) {
        const float bb = b2[(w + ct2 * 4) * 16 + ar];
#pragma unroll
        for (int rt = 0; rt < 4; ++rt) acc2[ct2][rt] = {bb, bb, bb, bb};
    }

#pragma unroll
    for (int hh = 0; hh < 2; ++hh) {
        // GEMM1 swapped: C[m=hidden][n=token] -> gelu -> packed write h[token][hidden]
#pragma unroll
        for (int i = 0; i < 4; ++i) {
            const int hcol0 = (w + 4 * i) * 16;         // within-half hidden base
            const int m0g = hh * 256 + hcol0;           // global hidden base
            bf16x8 af[4];
            float4 bb4;
            if (hh == 0 && i == 0) {
#pragma unroll
                for (int kc = 0; kc < 4; ++kc) af[kc] = pfw1[kc];
                bb4 = pfb1;
            } else {
#pragma unroll
                for (int kc = 0; kc < 4; ++kc)
                    af[kc] = *reinterpret_cast<const bf16x8*>(w1T + (m0g + ar) * 128 + kc * 32 + (kg << 3));
                bb4 = *reinterpret_cast<const float4*>(b1 + m0g + kg * 4);
            }
#pragma unroll
            for (int nt = 0; nt < 4; ++nt) {
                f32x4 c = {bb4.x, bb4.y, bb4.z, bb4.w};
#pragma unroll
                for (int kc = 0; kc < 4; ++kc)
                    c = __builtin_amdgcn_mfma_f32_16x16x32_bf16(af[kc], bx[nt][kc], c, 0, 0, 0);
                f32x4 g4;
#pragma unroll
                for (int r = 0; r < 4; ++r) {
                    const float v = c[r];
                    const float u = v * fmaf(0.044715f, v * v, 1.0f);
                    const float e = __expf(-1.5957691216057308f * u);   // exp(-2t)
                    g4[r] = v * __builtin_amdgcn_rcpf(1.0f + e);        // v*sigmoid(2t)
                }
                lds_wr4(s_h, nt * 16 + ar, hcol0 + kg * 4, 512, g4);
            }
        }
        // prefetch first GEMM2 weight of this half (hides under barrier drain)
        bf16x8 pfw2[2];
#pragma unroll
        for (int ct2 = 0; ct2 < 2; ++ct2)
            pfw2[ct2] = *reinterpret_cast<const bf16x8*>(w2T + ((w + ct2 * 4) * 16 + ar) * 512 + hh * 256 + (kg << 3));
        __syncthreads();
        // GEMM2 partial: y += h_half @ w2[hh*256..]
#pragma unroll
        for (int kc = 0; kc < 8; ++kc) {
            bf16x8 ah[4];
#pragma unroll
            for (int rt = 0; rt < 4; ++rt)
                ah[rt] = lds_frag(s_h, rt * 16 + ar, kc * 64 + (kg << 4), 512);
#pragma unroll
            for (int ct2 = 0; ct2 < 2; ++ct2) {
                const int brow = (w + ct2 * 4) * 16 + ar;
                const bf16x8 bw = (kc == 0) ? pfw2[ct2]
                    : *reinterpret_cast<const bf16x8*>(w2T + brow * 512 + hh * 256 + kc * 32 + (kg << 3));
#pragma unroll
                for (int rt = 0; rt < 4; ++rt)
                    acc2[ct2][rt] = __builtin_amdgcn_mfma_f32_16x16x32_bf16(ah[rt], bw, acc2[ct2][rt], 0, 0, 0);
            }
        }
        __syncthreads();
    }

    // ---------- phase 8: stage MLP out (f32 [64][132] @ smem+0), final write ----------
#pragma unroll
    for (int ct2 = 0; ct2 < 2; ++ct2)
#pragma unroll
        for (int rt = 0; rt < 4; ++rt)
#pragma unroll
            for (int r = 0; r < 4; ++r)
                s_out[(rt * 16 + kg * 4 + r) * 132 + (w + ct2 * 4) * 16 + ar] = acc2[ct2][rt][r];
    __syncthreads();
    {
        const int base = s_base[row];
        float* op = out + base + l4 * 32;
        const float* po = s_out + row * 132 + l4 * 32;
#pragma unroll
        for (int i = 0; i < 8; ++i) {
            float4 o;
            o.x = vals[4*i+0] + po[4*i+0];
            o.y = vals[4*i+1] + po[4*i+1];
            o.z = vals[4*i+2] + po[4*i+2];
            o.w = vals[4*i+3] + po[4*i+3];
            reinterpret_cast<float4*>(op)[i] = o;
        }
    }
}

extern "C" void kernel_launch(void* const* d_in, const int* in_sizes, int n_in,
                              void* d_out, int out_size, void* d_ws, size_t ws_size,
                              hipStream_t stream) {
    (void)in_sizes; (void)n_in; (void)ws_size; (void)out_size;
    const float* x    = (const float*)d_in[0];
    const float* wq   = (const float*)d_in[1];
    const float* bq   = (const float*)d_in[2];
    const float* wk   = (const float*)d_in[3];
    const float* bk   = (const float*)d_in[4];
    const float* wv   = (const float*)d_in[5];
    const float* bv   = (const float*)d_in[6];
    const float* wp   = (const float*)d_in[7];
    const float* bp   = (const float*)d_in[8];
    const float* rpb  = (const float*)d_in[9];
    const float* ln1g = (const float*)d_in[10];
    const float* ln1b = (const float*)d_in[11];
    const float* ln2g = (const float*)d_in[12];
    const float* ln2b = (const float*)d_in[13];
    const float* w1   = (const float*)d_in[14];
    const float* b1   = (const float*)d_in[15];
    const float* w2   = (const float*)d_in[16];
    const float* b2   = (const float*)d_in[17];
    const float* gate = (const float*)d_in[18];
    float* out = (float*)d_out;

    __bf16* ws = (__bf16*)d_ws;
    const __bf16* wqT = ws;
    const __bf16* wkT = ws + 16384;
    const __bf16* wvT = ws + 32768;
    const __bf16* wpT = ws + 49152;
    const __bf16* w1T = ws + 65536;
    const __bf16* w2T = ws + 131072;
    const float* wsf  = (const float*)(ws + 196608);
    const float* bias_pre = wsf;
    const float* bqs      = wsf + 8192;

    convert_w<<<801, 256, 0, stream>>>(wq, wk, wv, wp, w1, w2, rpb, bq, ws);
    swin_fused_kernel<<<8192, TPB, 0, stream>>>(x, wqT, wkT, bk, wvT, bv, wpT, bp,
                                                bias_pre, bqs, ln1g, ln1b, ln2g, ln2b,
                                                w1T, b1, w2T, b2, gate, out);
}

// Round 17
// 657.128 us; speedup vs baseline: 1.3054x; 1.0055x over previous
//
#include <hip/hip_runtime.h>
#include <hip/hip_bf16.h>
#include <math.h>

#define TPB 256

typedef __attribute__((ext_vector_type(8))) __bf16 bf16x8;
typedef __attribute__((ext_vector_type(4))) __bf16 bf16x4;
typedef __attribute__((ext_vector_type(4))) float f32x4;

// ---- swizzled LDS helpers: byte = row*rowBytes + (byteOff ^ ((row&7)<<4)) ----
static __device__ __forceinline__ bf16x8 lds_frag(const char* base, int row, int byteOff, int rowBytes) {
    return *reinterpret_cast<const bf16x8*>(base + row * rowBytes + (byteOff ^ ((row & 7) << 4)));
}
// packed 4x bf16 write (col0 must be multiple of 4)
static __device__ __forceinline__ void lds_wr4(char* base, int row, int col0, int rowBytes, f32x4 v) {
    bf16x4 p;
    p[0] = (__bf16)v[0]; p[1] = (__bf16)v[1]; p[2] = (__bf16)v[2]; p[3] = (__bf16)v[3];
    *reinterpret_cast<bf16x4*>(base + row * rowBytes + ((col0 << 1) ^ ((row & 7) << 4))) = p;
}

// ws layout: bf16 weights then f32 region
//   wqT@0 (scaled 0.25), wkT@16384, wvT@32768, wpT@49152, w1T@65536 [512][128], w2T@131072 [128][512]
//   f32 @ element 196608: bias_pre[8192] (SWAPPED-scores C-frag layout), bq_s[128]
__global__ void convert_w(const float* __restrict__ wq, const float* __restrict__ wk,
                          const float* __restrict__ wv, const float* __restrict__ wp,
                          const float* __restrict__ w1, const float* __restrict__ w2,
                          const float* __restrict__ rpb, const float* __restrict__ bq,
                          __bf16* __restrict__ ws)
{
    int g = blockIdx.x * 256 + threadIdx.x;
    if (g < 65536) {
        int which = g >> 14, idx = g & 16383, n = idx >> 7, k = idx & 127;
        const float* W = (which == 0) ? wq : (which == 1) ? wk : (which == 2) ? wv : wp;
        float v = W[k * 128 + n];
        if (which == 0) v *= 0.25f;                 // fold score scale into wq
        ws[g] = (__bf16)v;
    } else if (g < 131072) {
        int idx = g - 65536, n = idx >> 7, k = idx & 127;
        ws[g] = (__bf16)w1[k * 512 + n];
    } else if (g < 196608) {
        int idx = g - 131072, n = idx >> 9, k = idx & 511;
        ws[g] = (__bf16)w2[k * 128 + n];
    } else if (g < 204800) {
        // SWAPPED scores: C[m=ktoken][n=packed qrow]; lane=(kg*16+ar), reg r
        float* wsf = (float*)(ws + 196608);
        int g2 = g - 196608;
        int hc = g2 >> 8, h = hc >> 2, ct = hc & 3;
        int lane = (g2 >> 2) & 63, kg = lane >> 4, ar = lane & 15, r = g2 & 3;
        int dy = (ar >> 2) - h + 7;
        int dx = (ar & 3) - (ct * 2 + (kg >> 1)) + 7;
        int hsrc = ((kg & 1) << 2) | r;
        wsf[g2] = rpb[(dy * 15 + dx) * 8 + hsrc];
    } else if (g < 204928) {
        float* wsf = (float*)(ws + 196608);
        wsf[8192 + (g - 204800)] = bq[g - 204800] * 0.25f;
    }
}

// LDS map (bytes) — R13 layout:
//  A 0..16384     : xn [64]x256B -> (P @4096+w*2048, attn @12288) -> proj f32[17][132]@0 -> s_h/s_out
//  B 16384..32768 : K [64]x256B -> s_h upper
//  C 32768..49152 : V^T [128]x128B -> xn2 [64]x256B
//  Q 49152..53248 : [16]x256B (dedicated)
//  tail: mu, rs, gate, base, vmean(f32)
#define O_P     4096
#define O_ATTN  12288
#define O_K     16384
#define O_VT    32768
#define O_Q     49152
#define O_MU    53248
#define O_RS    53504
#define O_GATE  53760
#define O_BASE  54016
#define O_VMEAN 54272
#define SMEM_SZ 54784

__global__ __launch_bounds__(TPB, 2) void swin_fused_kernel(
    const float* __restrict__ x,
    const __bf16* __restrict__ wqT,               // pre-scaled by 0.25
    const __bf16* __restrict__ wkT, const float* __restrict__ bk,
    const __bf16* __restrict__ wvT, const float* __restrict__ bv,
    const __bf16* __restrict__ wpT, const float* __restrict__ bp,
    const float* __restrict__ bias_pre, const float* __restrict__ bqs,
    const float* __restrict__ ln1g, const float* __restrict__ ln1b,
    const float* __restrict__ ln2g, const float* __restrict__ ln2b,
    const __bf16* __restrict__ w1T, const float* __restrict__ b1,
    const __bf16* __restrict__ w2T, const float* __restrict__ b2,
    const float* __restrict__ gate,
    float* __restrict__ out)
{
    __shared__ __align__(16) char smem[SMEM_SZ];
    char* s_xn   = smem;                 // phase 1-2
    char* s_attn = smem + O_ATTN;
    char* s_k    = smem + O_K;
    char* s_vT   = smem + O_VT;
    char* s_xn2  = smem + O_VT;          // phase 5+
    char* s_q    = smem + O_Q;
    char* s_h    = smem;                 // phase 6 ([64]x512B)
    float* s_proj = (float*)(smem);      // phase 4-5, f32 [17][132]
    float* s_out  = (float*)(smem);      // phase 8, f32 [64][132]
    float* s_mu   = (float*)(smem + O_MU);
    float* s_rs   = (float*)(smem + O_RS);
    float* s_gate = (float*)(smem + O_GATE);
    int*   s_base = (int*)(smem + O_BASE);
    float* s_vmean = (float*)(smem + O_VMEAN);

    const int tid = threadIdx.x;
    const int blk = blockIdx.x;
    const int b  = blk >> 10;
    const int wh = (blk >> 5) & 31;
    const int ww = blk & 31;

    const int row = tid >> 2;     // token row for per-token phases
    const int l4  = tid & 3;
    const int lane = tid & 63, w = tid >> 6;
    const int ar = lane & 15, kg = lane >> 4;

    float vals[32];               // raw x phases 1-5, x2 phases 5-8

    // ---------- phase 1: load + LN1 (shift folded into addressing) ----------
    {
        const int si = wh * 8 + (row >> 3), sj = ww * 8 + (row & 7);
        const int oi = (si + 4) & 255, oj = (sj + 4) & 255;
        const int base = ((b * 256 + oi) * 256 + oj) * 128;
        if (l4 == 0) { s_base[row] = base; s_gate[row] = gate[oi * 256 + oj]; }
        const float* xp = x + base + l4 * 32;
        float sum = 0.f, sq = 0.f;
#pragma unroll
        for (int i = 0; i < 8; ++i) {
            const float4 v4 = reinterpret_cast<const float4*>(xp)[i];
            vals[4*i+0] = v4.x; vals[4*i+1] = v4.y; vals[4*i+2] = v4.z; vals[4*i+3] = v4.w;
            sum += v4.x + v4.y + v4.z + v4.w;
            sq  += v4.x*v4.x + v4.y*v4.y + v4.z*v4.z + v4.w*v4.w;
        }
        sum += __shfl_xor(sum, 1); sum += __shfl_xor(sum, 2);
        sq  += __shfl_xor(sq , 1); sq  += __shfl_xor(sq , 2);
        const float mu  = sum * (1.f / 128.f);
        const float var = sq * (1.f / 128.f) - mu * mu;
        const float rs  = rsqrtf(var + 1e-5f);
        if (l4 == 0) { s_mu[row] = mu; s_rs[row] = rs; }
#pragma unroll
        for (int j = 0; j < 4; ++j) {
            bf16x8 pk;
#pragma unroll
            for (int e = 0; e < 8; ++e) {
                const int d = l4 * 32 + j * 8 + e;
                pk[e] = (__bf16)((vals[j*8+e] - mu) * rs * ln1g[d] + ln1b[d]);
            }
            const int byteOff = (l4 * 64 + j * 16) ^ ((row & 7) << 4);
            *reinterpret_cast<bf16x8*>(s_xn + row * 256 + byteOff) = pk;
        }
    }

    // ---- prefetch phase-2 K/V weights + biases (pure global reg-loads) ----
    bf16x8 pfk[2][4], pfv[2][4];
    float4 pfbk[2];
    float  pfbv[2];
#pragma unroll
    for (int ct2 = 0; ct2 < 2; ++ct2) {
        const int m0t = (w + ct2 * 4) * 16;
#pragma unroll
        for (int kc = 0; kc < 4; ++kc) {
            pfk[ct2][kc] = *reinterpret_cast<const bf16x8*>(wkT + (m0t + ar) * 128 + kc * 32 + (kg << 3));
            pfv[ct2][kc] = *reinterpret_cast<const bf16x8*>(wvT + (m0t + ar) * 128 + kc * 32 + (kg << 3));
        }
        pfbk[ct2] = *reinterpret_cast<const float4*>(bk + m0t + kg * 4);
        pfbv[ct2] = bv[m0t + ar];
    }
    __syncthreads();

    // ---------- phase 2 (merged): K + V + Q GEMMs ----------
    f32x4 pfcin[2][4];   // bias_pre prefetch for phase 3
    {
        bf16x8 a[4][4];    // xn token-tiles (B-operand for swapped GEMMs)
#pragma unroll
        for (int nt = 0; nt < 4; ++nt)
#pragma unroll
            for (int kc = 0; kc < 4; ++kc)
                a[nt][kc] = lds_frag(s_xn, nt * 16 + ar, kc * 64 + (kg << 4), 256);
        const int nrow = ((ar >> 2) << 3) + (ar & 3);   // unmasked token for packed row ar
        bf16x8 aq[4];
#pragma unroll
        for (int kc = 0; kc < 4; ++kc)
            aq[kc] = lds_frag(s_xn, nrow, kc * 64 + (kg << 4), 256);

        // K swapped: C[m=kcol][n=token] -> packed writes s_k[token][kcol]
#pragma unroll
        for (int ct2 = 0; ct2 < 2; ++ct2) {
            const int m0t = (w + ct2 * 4) * 16;
#pragma unroll
            for (int nt = 0; nt < 4; ++nt) {
                f32x4 c = {pfbk[ct2].x, pfbk[ct2].y, pfbk[ct2].z, pfbk[ct2].w};
#pragma unroll
                for (int kc = 0; kc < 4; ++kc)
                    c = __builtin_amdgcn_mfma_f32_16x16x32_bf16(pfk[ct2][kc], a[nt][kc], c, 0, 0, 0);
                lds_wr4(s_k, nt * 16 + ar, m0t + kg * 4, 256, c);
            }
        }
        // V unswapped: C[m=token][n=vcol] -> packed writes s_vT[vcol][token] + col-mean
#pragma unroll
        for (int ct2 = 0; ct2 < 2; ++ct2) {
            const int brow = (w + ct2 * 4) * 16 + ar;
            const float bb = pfbv[ct2];
            float vs = 0.f;
#pragma unroll
            for (int rt = 0; rt < 4; ++rt) {
                f32x4 c = {bb, bb, bb, bb};
#pragma unroll
                for (int kc = 0; kc < 4; ++kc)
                    c = __builtin_amdgcn_mfma_f32_16x16x32_bf16(a[rt][kc], pfv[ct2][kc], c, 0, 0, 0);
                lds_wr4(s_vT, brow, rt * 16 + kg * 4, 128, c);
                vs += c[0] + c[1] + c[2] + c[3];
            }
            vs += __shfl_xor(vs, 16); vs += __shfl_xor(vs, 32);
            if (kg == 0) s_vmean[brow] = vs * (1.f / 64.f);
        }
        // Q swapped -> dedicated s_q region
#pragma unroll
        for (int ct2 = 0; ct2 < 2; ++ct2) {
            const int m0t = (w + ct2 * 4) * 16;
            bf16x8 af[4];
#pragma unroll
            for (int kc = 0; kc < 4; ++kc)
                af[kc] = *reinterpret_cast<const bf16x8*>(wqT + (m0t + ar) * 128 + kc * 32 + (kg << 3));
            const float4 bb4 = *reinterpret_cast<const float4*>(bqs + m0t + kg * 4);
            f32x4 c = {bb4.x, bb4.y, bb4.z, bb4.w};
#pragma unroll
            for (int kc = 0; kc < 4; ++kc)
                c = __builtin_amdgcn_mfma_f32_16x16x32_bf16(af[kc], aq[kc], c, 0, 0, 0);
            lds_wr4(s_q, ar, m0t + kg * 4, 256, c);
        }
        // prefetch phase-3 bias_pre fragments
#pragma unroll
        for (int hi = 0; hi < 2; ++hi) {
            const int h = w + hi * 4;
#pragma unroll
            for (int ct = 0; ct < 4; ++ct)
                pfcin[hi][ct] = *reinterpret_cast<const f32x4*>(bias_pre + ((h * 4 + ct) << 8) + (lane << 2));
        }
    }
    __syncthreads();

    // ---------- phase 3: attention (wave w: heads w, w+4), swapped scores/PV ----------
    char* s_p = smem + O_P + (w << 11);
#pragma unroll
    for (int hi = 0; hi < 2; ++hi) {
        const int h = w + hi * 4;
        bf16x8 aQ = {};
        if (lane < 32) aQ = lds_frag(s_q, ar, h * 32 + (kg << 4), 256);
        f32x4 sc[4];
#pragma unroll
        for (int ct = 0; ct < 4; ++ct) {
            bf16x8 bK = {};
            if (lane < 32) bK = lds_frag(s_k, ct * 16 + ar, h * 32 + (kg << 4), 256);
            sc[ct] = __builtin_amdgcn_mfma_f32_16x16x32_bf16(bK, aQ, pfcin[hi][ct], 0, 0, 0);
        }
        float sm = 0.f;
#pragma unroll
        for (int ct = 0; ct < 4; ++ct)
#pragma unroll
            for (int r = 0; r < 4; ++r) {
                sc[ct][r] = __expf(sc[ct][r]);
                sm += sc[ct][r];
            }
        sm += __shfl_xor(sm, 16); sm += __shfl_xor(sm, 32);
        const float inv = __builtin_amdgcn_rcpf(sm);
#pragma unroll
        for (int ct = 0; ct < 4; ++ct) {
            f32x4 p4 = {sc[ct][0] * inv, sc[ct][1] * inv, sc[ct][2] * inv, sc[ct][3] * inv};
            lds_wr4(s_p, ar, ct * 16 + kg * 4, 128, p4);
        }
        // PV swapped: C[m=vcol][n=qrow] -> packed write s_attn[qrow][vcol]
        f32x4 o = {0.f, 0.f, 0.f, 0.f};
#pragma unroll
        for (int kc = 0; kc < 2; ++kc) {
            bf16x8 ap = lds_frag(s_p,  ar, kc * 64 + (kg << 4), 128);
            bf16x8 bV = lds_frag(s_vT, h * 16 + ar, kc * 64 + (kg << 4), 128);
            o = __builtin_amdgcn_mfma_f32_16x16x32_bf16(bV, ap, o, 0, 0, 0);
        }
        lds_wr4(s_attn, ar, h * 16 + kg * 4, 256, o);
    }
    // ---- prefetch phase-4 proj weights ----
    bf16x8 pfp[2][4];
    float  pfbp[2];
#pragma unroll
    for (int ct2 = 0; ct2 < 2; ++ct2) {
        const int brow = (w + ct2 * 4) * 16 + ar;
#pragma unroll
        for (int kc = 0; kc < 4; ++kc)
            pfp[ct2][kc] = *reinterpret_cast<const bf16x8*>(wpT + brow * 128 + kc * 32 + (kg << 3));
        pfbp[ct2] = bp[brow];
    }
    __syncthreads();

    // ---------- phase 4: proj (M=16 packed rows) + V_mean proj (all 256 threads) ----------
    {
        bf16x8 a2[4];
#pragma unroll
        for (int kc = 0; kc < 4; ++kc)
            a2[kc] = lds_frag(s_attn, ar, kc * 64 + (kg << 4), 256);
#pragma unroll
        for (int ct2 = 0; ct2 < 2; ++ct2) {
            const int brow = (w + ct2 * 4) * 16 + ar;
            const float bb = pfbp[ct2];
            f32x4 c = {bb, bb, bb, bb};
#pragma unroll
            for (int kc = 0; kc < 4; ++kc)
                c = __builtin_amdgcn_mfma_f32_16x16x32_bf16(a2[kc], pfp[ct2][kc], c, 0, 0, 0);
#pragma unroll
            for (int r = 0; r < 4; ++r)
                s_proj[(kg * 4 + r) * 132 + brow] = c[r];
        }
        // V_mean proj row: col = tid>>1, each half-thread does 8 of 16 j-steps, shfl combine
        {
            const int col  = tid >> 1;
            const int half = tid & 1;
            float acc = half ? 0.f : bp[col];
#pragma unroll
            for (int jj = 0; jj < 8; ++jj) {
                const int j = half * 8 + jj;
                const bf16x8 w8 = *reinterpret_cast<const bf16x8*>(wpT + col * 128 + j * 8);
                const f32x4 vm0 = *reinterpret_cast<const f32x4*>(s_vmean + j * 8);
                const f32x4 vm1 = *reinterpret_cast<const f32x4*>(s_vmean + j * 8 + 4);
                acc += vm0[0] * (float)w8[0] + vm0[1] * (float)w8[1]
                     + vm0[2] * (float)w8[2] + vm0[3] * (float)w8[3]
                     + vm1[0] * (float)w8[4] + vm1[1] * (float)w8[5]
                     + vm1[2] * (float)w8[6] + vm1[3] * (float)w8[7];
            }
            acc += __shfl_xor(acc, 1);
            if (half == 0) s_proj[16 * 132 + col] = acc;
        }
    }

    // ---- prefetch phase-5 LN1 gamma/beta (first half) during phase-4 tail ----
    float4 pfg[4], pfbv4[4];
#pragma unroll
    for (int i = 0; i < 4; ++i) {
        pfg[i]   = reinterpret_cast<const float4*>(ln1g + l4 * 32)[i];
        pfbv4[i] = reinterpret_cast<const float4*>(ln1b + l4 * 32)[i];
    }
    __syncthreads();

    // ---------- phase 5: assemble x2 (f32 xn recompute) + LN2 -> xn2 into C ----------
    {
        const float sg = 1.f / (1.f + __expf(-s_gate[row]));
        const float mu1 = s_mu[row], rs1 = s_rs[row];
        const bool masked = ((row >> 3) >= 4) || ((row & 7) >= 4);
        const int prow = masked ? 16 : ((row >> 3) * 4 + (row & 7));
        const float* pr = s_proj + prow * 132 + l4 * 32;
        const float* g1  = ln1g + l4 * 32;
        const float* b1v = ln1b + l4 * 32;
        float sum = 0.f, sq = 0.f;
#pragma unroll
        for (int i = 0; i < 8; ++i) {
            const float4 gg = (i < 4) ? pfg[i]   : reinterpret_cast<const float4*>(g1)[i];
            const float4 bb = (i < 4) ? pfbv4[i] : reinterpret_cast<const float4*>(b1v)[i];
            const float g4[4] = {gg.x, gg.y, gg.z, gg.w};
            const float b4[4] = {bb.x, bb.y, bb.z, bb.w};
#pragma unroll
            for (int c = 0; c < 4; ++c) {
                const int idx = 4*i + c;
                const float xv = vals[idx];
                const float xnv = (xv - mu1) * rs1 * g4[c] + b4[c];
                const float x2 = xnv + pr[idx] + sg * xv;
                vals[idx] = x2;
                sum += x2; sq += x2 * x2;
            }
        }
        sum += __shfl_xor(sum, 1); sum += __shfl_xor(sum, 2);
        sq  += __shfl_xor(sq , 1); sq  += __shfl_xor(sq , 2);
        const float mu  = sum * (1.f / 128.f);
        const float var = sq * (1.f / 128.f) - mu * mu;
        const float rs  = rsqrtf(var + 1e-5f);
        // xn2 writes (region C) are disjoint from s_proj reads (region A): no barrier needed
#pragma unroll
        for (int j = 0; j < 4; ++j) {
            bf16x8 pk;
#pragma unroll
            for (int e = 0; e < 8; ++e) {
                const int d = l4 * 32 + j * 8 + e;
                pk[e] = (__bf16)((vals[j*8+e] - mu) * rs * ln2g[d] + ln2b[d]);
            }
            const int byteOff = (l4 * 64 + j * 16) ^ ((row & 7) << 4);
            *reinterpret_cast<bf16x8*>(s_xn2 + row * 256 + byteOff) = pk;
        }
    }
    __syncthreads();

    // ---------- phase 6/7: MLP, GEMM1 swapped (packed h writes), hidden in 2 halves ----------
    bf16x8 bx[4][4];
#pragma unroll
    for (int nt = 0; nt < 4; ++nt)
#pragma unroll
        for (int kc = 0; kc < 4; ++kc)
            bx[nt][kc] = lds_frag(s_xn2, nt * 16 + ar, kc * 64 + (kg << 4), 256);

    f32x4 acc2[2][4];
#pragma unroll
    for (int ct2 = 0; ct2 < 2; ++ct2) {
        const float bb = b2[(w + ct2 * 4) * 16 + ar];
#pragma unroll
        for (int rt = 0; rt < 4; ++rt) acc2[ct2][rt] = {bb, bb, bb, bb};
    }

#pragma unroll
    for (int hh = 0; hh < 2; ++hh) {
        // GEMM1 swapped: C[m=hidden][n=token] -> gelu -> packed write h[token][hidden]
#pragma unroll
        for (int i = 0; i < 4; ++i) {
            const int hcol0 = (w + 4 * i) * 16;         // within-half hidden base
            const int m0g = hh * 256 + hcol0;           // global hidden base
            bf16x8 af[4];
#pragma unroll
            for (int kc = 0; kc < 4; ++kc)
                af[kc] = *reinterpret_cast<const bf16x8*>(w1T + (m0g + ar) * 128 + kc * 32 + (kg << 3));
            const float4 bb4 = *reinterpret_cast<const float4*>(b1 + m0g + kg * 4);
#pragma unroll
            for (int nt = 0; nt < 4; ++nt) {
                f32x4 c = {bb4.x, bb4.y, bb4.z, bb4.w};
#pragma unroll
                for (int kc = 0; kc < 4; ++kc)
                    c = __builtin_amdgcn_mfma_f32_16x16x32_bf16(af[kc], bx[nt][kc], c, 0, 0, 0);
                f32x4 g4;
#pragma unroll
                for (int r = 0; r < 4; ++r) {
                    const float v = c[r];
                    const float u = v * fmaf(0.044715f, v * v, 1.0f);
                    const float e = __expf(-1.5957691216057308f * u);   // exp(-2t)
                    g4[r] = v * __builtin_amdgcn_rcpf(1.0f + e);        // v*sigmoid(2t)
                }
                lds_wr4(s_h, nt * 16 + ar, hcol0 + kg * 4, 512, g4);
            }
        }
        // prefetch first GEMM2 weight of this half (hides under barrier drain)
        bf16x8 pfw2[2];
#pragma unroll
        for (int ct2 = 0; ct2 < 2; ++ct2)
            pfw2[ct2] = *reinterpret_cast<const bf16x8*>(w2T + ((w + ct2 * 4) * 16 + ar) * 512 + hh * 256 + (kg << 3));
        __syncthreads();
        // GEMM2 partial: y += h_half @ w2[hh*256..]
#pragma unroll
        for (int kc = 0; kc < 8; ++kc) {
            bf16x8 ah[4];
#pragma unroll
            for (int rt = 0; rt < 4; ++rt)
                ah[rt] = lds_frag(s_h, rt * 16 + ar, kc * 64 + (kg << 4), 512);
#pragma unroll
            for (int ct2 = 0; ct2 < 2; ++ct2) {
                const int brow = (w + ct2 * 4) * 16 + ar;
                const bf16x8 bw = (kc == 0) ? pfw2[ct2]
                    : *reinterpret_cast<const bf16x8*>(w2T + brow * 512 + hh * 256 + kc * 32 + (kg << 3));
#pragma unroll
                for (int rt = 0; rt < 4; ++rt)
                    acc2[ct2][rt] = __builtin_amdgcn_mfma_f32_16x16x32_bf16(ah[rt], bw, acc2[ct2][rt], 0, 0, 0);
            }
        }
        __syncthreads();
    }

    // ---------- phase 8: stage MLP out (f32 [64][132] @ smem+0), final write ----------
#pragma unroll
    for (int ct2 = 0; ct2 < 2; ++ct2)
#pragma unroll
        for (int rt = 0; rt < 4; ++rt)
#pragma unroll
            for (int r = 0; r < 4; ++r)
                s_out[(rt * 16 + kg * 4 + r) * 132 + (w + ct2 * 4) * 16 + ar] = acc2[ct2][rt][r];
    __syncthreads();
    {
        const int base = s_base[row];
        float* op = out + base + l4 * 32;
        const float* po = s_out + row * 132 + l4 * 32;
#pragma unroll
        for (int i = 0; i < 8; ++i) {
            float4 o;
            o.x = vals[4*i+0] + po[4*i+0];
            o.y = vals[4*i+1] + po[4*i+1];
            o.z = vals[4*i+2] + po[4*i+2];
            o.w = vals[4*i+3] + po[4*i+3];
            reinterpret_cast<float4*>(op)[i] = o;
        }
    }
}

extern "C" void kernel_launch(void* const* d_in, const int* in_sizes, int n_in,
                              void* d_out, int out_size, void* d_ws, size_t ws_size,
                              hipStream_t stream) {
    (void)in_sizes; (void)n_in; (void)ws_size; (void)out_size;
    const float* x    = (const float*)d_in[0];
    const float* wq   = (const float*)d_in[1];
    const float* bq   = (const float*)d_in[2];
    const float* wk   = (const float*)d_in[3];
    const float* bk   = (const float*)d_in[4];
    const float* wv   = (const float*)d_in[5];
    const float* bv   = (const float*)d_in[6];
    const float* wp   = (const float*)d_in[7];
    const float* bp   = (const float*)d_in[8];
    const float* rpb  = (const float*)d_in[9];
    const float* ln1g = (const float*)d_in[10];
    const float* ln1b = (const float*)d_in[11];
    const float* ln2g = (const float*)d_in[12];
    const float* ln2b = (const float*)d_in[13];
    const float* w1   = (const float*)d_in[14];
    const float* b1   = (const float*)d_in[15];
    const float* w2   = (const float*)d_in[16];
    const float* b2   = (const float*)d_in[17];
    const float* gate = (const float*)d_in[18];
    float* out = (float*)d_out;

    __bf16* ws = (__bf16*)d_ws;
    const __bf16* wqT = ws;
    const __bf16* wkT = ws + 16384;
    const __bf16* wvT = ws + 32768;
    const __bf16* wpT = ws + 49152;
    const __bf16* w1T = ws + 65536;
    const __bf16* w2T = ws + 131072;
    const float* wsf  = (const float*)(ws + 196608);
    const float* bias_pre = wsf;
    const float* bqs      = wsf + 8192;

    convert_w<<<801, 256, 0, stream>>>(wq, wk, wv, wp, w1, w2, rpb, bq, ws);
    swin_fused_kernel<<<8192, TPB, 0, stream>>>(x, wqT, wkT, bk, wvT, bv, wpT, bp,
                                                bias_pre, bqs, ln1g, ln1b, ln2g, ln2b,
                                                w1T, b1, w2T, b2, gate, out);
}